// Round 2
// baseline (14589.468 us; speedup 1.0000x reference)
//
#include <hip/hip_runtime.h>

typedef unsigned short u16;
typedef unsigned int u32;
typedef unsigned long long u64;
typedef __attribute__((ext_vector_type(4))) float f32x4;
typedef __attribute__((ext_vector_type(8))) short bf16x8;

#define S_LEN 2048
#define BATCH 32
#define HID 512
#define NG 2048           // 4*HID
#define NWG 64            // recurrence workgroups per layer
#define SLICE 8           // hidden units per WG (HID/NWG)

#define MFMA16(a, b, c) __builtin_amdgcn_mfma_f32_16x16x32_bf16((a), (b), (c), 0, 0, 0)

__device__ __forceinline__ u16 f2bf(float f) {
  u32 u = __builtin_bit_cast(u32, f);
  u32 r = (u + 0x7FFFu + ((u >> 16) & 1u)) >> 16;   // RNE
  return (u16)r;
}
__device__ __forceinline__ float bf2f(u16 u) {
  u32 x = ((u32)u) << 16;
  return __builtin_bit_cast(float, x);
}
__device__ __forceinline__ float sigf(float x) {
  return 1.0f / (1.0f + __expf(-x));
}
__device__ __forceinline__ float tanh_fast(float x) {
  float a = fabsf(x);
  float t = __expf(-2.0f * a);
  float r = (1.0f - t) / (1.0f + t);
  return x < 0.0f ? -r : r;
}

// ---------------------------------------------------------------------------
// Weight prep: fp32 -> bf16 copies of W_ih / W_hh, bias sum.
// ---------------------------------------------------------------------------
__global__ void prep_weights(const float* __restrict__ Wih, const float* __restrict__ Whh,
                             const float* __restrict__ bih, const float* __restrict__ bhh,
                             u16* __restrict__ wih_bf, u16* __restrict__ whh_bf,
                             float* __restrict__ bsum) {
  const int i = blockIdx.x * 256 + threadIdx.x;   // grid covers exactly 2*NG*HID
  wih_bf[i] = f2bf(Wih[i]);
  whh_bf[i] = f2bf(Whh[i]);
  if (i < 2 * NG) bsum[i] = bih[i] + bhh[i];
}

// ---------------------------------------------------------------------------
// GEMM (layer-1 input contribution only):
//   xg[r][n] = sum_k X[b][t][k] * Wih1[n][k] + bias[n],  r = t*32+b
// 64x64 tiles, BK=64, 256 threads (4 waves, 2x2 quadrants of 32x32 each).
// ---------------------------------------------------------------------------
__global__ __launch_bounds__(256)
void gemm_xg(const float* __restrict__ Ap, const u16* __restrict__ Bw,
             const float* __restrict__ bias, void* __restrict__ xgp, int xg32)
{
  __shared__ __align__(16) u16 aT[64][72];
  __shared__ __align__(16) u16 bT[64][72];
  const int tid = threadIdx.x;
  const int nb = blockIdx.x;     // 0..31 (N tiles)
  const int mb = blockIdx.y;     // 0..1023 (M tiles)
  const int lane = tid & 63, wid = tid >> 6;
  const int mw = (wid & 1) * 32, nw = (wid >> 1) * 32;
  f32x4 acc[2][2] = {{{0.f,0.f,0.f,0.f},{0.f,0.f,0.f,0.f}},
                     {{0.f,0.f,0.f,0.f},{0.f,0.f,0.f,0.f}}};

  const int arow = tid >> 2;
  const int gm = mb * 64 + arow;
  const int t = gm >> 5, b = gm & 31;
  const size_t aoff = ((size_t)b * S_LEN + t) * HID;
  const size_t boff = (size_t)(nb * 64 + arow) * HID;
  const int c16 = (tid & 3) * 16;

  for (int kb = 0; kb < 8; ++kb) {
    const int k0 = kb * 64;
    {
      const float* src = Ap + aoff + k0 + c16;
      #pragma unroll
      for (int q = 0; q < 4; ++q) {
        const float4 v = ((const float4*)src)[q];
        ushort4 w4;
        w4.x = f2bf(v.x); w4.y = f2bf(v.y); w4.z = f2bf(v.z); w4.w = f2bf(v.w);
        *(ushort4*)&aT[arow][c16 + q * 4] = w4;
      }
    }
    {
      const uint4* src = (const uint4*)(Bw + boff + k0 + c16);
      const uint4 v0 = src[0], v1 = src[1];
      *(uint4*)&bT[arow][c16] = v0;
      *(uint4*)&bT[arow][c16 + 8] = v1;
    }
    __syncthreads();
    #pragma unroll
    for (int kk = 0; kk < 2; ++kk) {
      const int ko = kk * 32 + (lane >> 4) * 8;
      const bf16x8 a0 = *(const bf16x8*)&aT[mw +      (lane & 15)][ko];
      const bf16x8 a1 = *(const bf16x8*)&aT[mw + 16 + (lane & 15)][ko];
      const bf16x8 b0 = *(const bf16x8*)&bT[nw +      (lane & 15)][ko];
      const bf16x8 b1 = *(const bf16x8*)&bT[nw + 16 + (lane & 15)][ko];
      acc[0][0] = MFMA16(a0, b0, acc[0][0]);
      acc[0][1] = MFMA16(a0, b1, acc[0][1]);
      acc[1][0] = MFMA16(a1, b0, acc[1][0]);
      acc[1][1] = MFMA16(a1, b1, acc[1][1]);
    }
    __syncthreads();
  }
  const int col = lane & 15, rb = (lane >> 4) * 4;
  #pragma unroll
  for (int fm = 0; fm < 2; ++fm) {
    #pragma unroll
    for (int fn = 0; fn < 2; ++fn) {
      const int gn = nb * 64 + nw + fn * 16 + col;
      const float bv = bias[gn];
      #pragma unroll
      for (int r = 0; r < 4; ++r) {
        const size_t gmr = (size_t)(mb * 64 + mw + fm * 16 + rb + r);
        const float v = acc[fm][fn][r] + bv;
        if (xg32) ((float*)xgp)[gmr * NG + gn] = v;
        else      ((u16*)xgp)[gmr * NG + gn] = f2bf(v);
      }
    }
  }
}

// ---------------------------------------------------------------------------
// Fused 2-layer LSTM recurrence. 128 persistent WGs:
//   blocks 0..63   -> layer 1 (reads precomputed xg1)
//   blocks 64..127 -> layer 2, lagging one step, computing Wih2 @ h1[t] on the
//                     fly from LDS-resident Wih2 slice (no layer-2 GEMM).
//
// Handoff protocol (fence-free):
//   producer: bypass (agent-relaxed) h stores -> barrier (vmcnt(0) drain)
//             -> relaxed flag store. h is at the L3 coherence point before
//             the flag is visible.
//   consumer: poll flags with bypass loads; then read h with PLAIN CACHED
//             uint4 loads. Safe because every step's h tile is a fresh
//             address range: written exactly once (by non-allocating bypass
//             stores) strictly before the flag, and first read by any cache
//             only after the flag. First reader per XCD misses L2 -> L3
//             (fresh); other WGs on that XCD hit L2. This converts the
//             64-way L3 broadcast into an 8-way one with pipelined 16B loads.
// ---------------------------------------------------------------------------
__global__ __launch_bounds__(256, 1)
void lstm_fused(const void* __restrict__ xgp, int xg32,
                const u16* __restrict__ whh_bf, const u16* __restrict__ wih_bf,
                const float* __restrict__ bsum,
                u16* __restrict__ hb1, u16* __restrict__ hb2,
                float* __restrict__ dout, u32* __restrict__ flags)
{
  __shared__ __align__(16) u16 wR[32][520];   // recurrent weight slice (this layer)
  __shared__ __align__(16) u16 wI[32][520];   // layer 2 only: Wih2 slice
  __shared__ __align__(16) u16 hA[32][520];   // h1[t] (L2) or h1[t-1] (L1)
  __shared__ __align__(16) u16 hB[32][520];   // layer 2 only: h2[t-1]
  __shared__ float gT[32][33];                // gate tile (batch x 32 gate cols)

  const int blk = blockIdx.x;
  const int layer = blk >> 6;
  const int w = blk & 63;
  const int tid = threadIdx.x;
  const int lane = tid & 63, wid = tid >> 6;
  const int mw = (wid & 1) * 16, nw = (wid >> 1) * 16;
  const int b = tid >> 3, j = tid & 7;
  u32* f_l1  = flags;            // layer-1 flags [64]
  u32* f_own = flags + layer * 64;

  // stage recurrent weight slice: local row r = g*8+jj -> gate row g*512+w*8+jj
  const u16* Whh = whh_bf + (size_t)layer * NG * HID;
  #pragma unroll
  for (int i = tid; i < 32 * 64; i += 256) {
    const int r = i >> 6, ch = i & 63;
    const int gnrow = (r >> 3) * HID + w * SLICE + (r & 7);
    *(uint4*)&wR[r][ch * 8] = *(const uint4*)&Whh[(size_t)gnrow * HID + ch * 8];
  }
  float bv[4] = {0.f, 0.f, 0.f, 0.f};
  if (layer == 1) {
    const u16* Wih2 = wih_bf + (size_t)NG * HID;
    #pragma unroll
    for (int i = tid; i < 32 * 64; i += 256) {
      const int r = i >> 6, ch = i & 63;
      const int gnrow = (r >> 3) * HID + w * SLICE + (r & 7);
      *(uint4*)&wI[r][ch * 8] = *(const uint4*)&Wih2[(size_t)gnrow * HID + ch * 8];
    }
    #pragma unroll
    for (int g = 0; g < 4; ++g) bv[g] = bsum[NG + g * HID + w * SLICE + j];
  }
  u16* hb_own = layer ? hb2 : hb1;
  float c = 0.0f;
  __syncthreads();

  for (int t = 0; t < S_LEN; ++t) {
    float xv[4];

    if (layer == 0) {
      // prefetch xg1 for this step; loads in flight across the flag wait.
      // non-temporal: xg is streamed once, keep it out of L2/L3 (h lives there)
      if (xg32) {
        const float* x = (const float*)xgp + ((size_t)t * BATCH + b) * NG + w * SLICE + j;
        #pragma unroll
        for (int g = 0; g < 4; ++g) xv[g] = __builtin_nontemporal_load(&x[g * HID]);
      } else {
        const u16* x = (const u16*)xgp + ((size_t)t * BATCH + b) * NG + w * SLICE + j;
        #pragma unroll
        for (int g = 0; g < 4; ++g) xv[g] = bf2f(__builtin_nontemporal_load(&x[g * HID]));
      }
    } else {
      #pragma unroll
      for (int g = 0; g < 4; ++g) xv[g] = bv[g];
    }

    // ---- flag waits (no fences; data path is fresh-address coherent) ----
    if (layer == 1) {
      if (wid == 0) {
        const u32 tgt = (u32)(t + 1);                 // h1[t] ready
        while (true) {
          u32 v = __hip_atomic_load(&f_l1[lane], __ATOMIC_RELAXED,
                                    __HIP_MEMORY_SCOPE_AGENT);
          if (__all((int)(v >= tgt))) break;
          __builtin_amdgcn_s_sleep(1);
        }
      } else if (wid == 1 && t > 0) {
        const u32 tgt = (u32)t;                       // own h2[t-1] ready
        while (true) {
          u32 v = __hip_atomic_load(&f_own[lane], __ATOMIC_RELAXED,
                                    __HIP_MEMORY_SCOPE_AGENT);
          if (__all((int)(v >= tgt))) break;
          __builtin_amdgcn_s_sleep(1);
        }
      }
    } else if (t > 0) {
      if (wid == 0) {
        const u32 tgt = (u32)t;                       // own h1[t-1] ready
        while (true) {
          u32 v = __hip_atomic_load(&f_own[lane], __ATOMIC_RELAXED,
                                    __HIP_MEMORY_SCOPE_AGENT);
          if (__all((int)(v >= tgt))) break;
          __builtin_amdgcn_s_sleep(1);
        }
      }
    }
    __syncthreads();

    // ---- stage h tiles (32x512 bf16 each) via plain cached 16B loads ----
    const u16* srcA = nullptr;
    const u16* srcB = nullptr;
    if (layer == 1) {
      srcA = hb1 + (size_t)t * (BATCH * HID);
      if (t > 0) srcB = hb2 + (size_t)(t - 1) * (BATCH * HID);
    } else if (t > 0) {
      srcA = hb1 + (size_t)(t - 1) * (BATCH * HID);
    }
    uint4 vA[8], vB[8];
    if (srcA) {
      #pragma unroll
      for (int ii = 0; ii < 8; ++ii) {
        const int i = tid + ii * 256, r = i >> 6, cc = i & 63;
        vA[ii] = *(const uint4*)(srcA + (size_t)r * HID + cc * 8);
      }
    }
    if (srcB) {
      #pragma unroll
      for (int ii = 0; ii < 8; ++ii) {
        const int i = tid + ii * 256, r = i >> 6, cc = i & 63;
        vB[ii] = *(const uint4*)(srcB + (size_t)r * HID + cc * 8);
      }
    }
    if (srcA) {
      #pragma unroll
      for (int ii = 0; ii < 8; ++ii) {
        const int i = tid + ii * 256, r = i >> 6, cc = i & 63;
        *(uint4*)&hA[r][cc * 8] = vA[ii];
      }
    }
    if (srcB) {
      #pragma unroll
      for (int ii = 0; ii < 8; ++ii) {
        const int i = tid + ii * 256, r = i >> 6, cc = i & 63;
        *(uint4*)&hB[r][cc * 8] = vB[ii];
      }
    }
    __syncthreads();

    // ---- MFMA: two independent accumulator chains halve dep latency ----
    f32x4 ac0 = {0.f,0.f,0.f,0.f}, ac1 = {0.f,0.f,0.f,0.f};
    if (layer == 1) {
      #pragma unroll
      for (int kt = 0; kt < 16; ++kt) {
        const int ko = kt * 32 + (lane >> 4) * 8;
        const bf16x8 a  = *(const bf16x8*)&hA[mw + (lane & 15)][ko];
        const bf16x8 bb = *(const bf16x8*)&wI[nw + (lane & 15)][ko];
        if (kt & 1) ac1 = MFMA16(a, bb, ac1); else ac0 = MFMA16(a, bb, ac0);
      }
      if (t > 0) {
        #pragma unroll
        for (int kt = 0; kt < 16; ++kt) {
          const int ko = kt * 32 + (lane >> 4) * 8;
          const bf16x8 a  = *(const bf16x8*)&hB[mw + (lane & 15)][ko];
          const bf16x8 bb = *(const bf16x8*)&wR[nw + (lane & 15)][ko];
          if (kt & 1) ac1 = MFMA16(a, bb, ac1); else ac0 = MFMA16(a, bb, ac0);
        }
      }
    } else if (t > 0) {
      #pragma unroll
      for (int kt = 0; kt < 16; ++kt) {
        const int ko = kt * 32 + (lane >> 4) * 8;
        const bf16x8 a  = *(const bf16x8*)&hA[mw + (lane & 15)][ko];
        const bf16x8 bb = *(const bf16x8*)&wR[nw + (lane & 15)][ko];
        if (kt & 1) ac1 = MFMA16(a, bb, ac1); else ac0 = MFMA16(a, bb, ac0);
      }
    }
    const f32x4 acc = ac0 + ac1;

    // gate tile -> LDS -> per-(b,j) elementwise
    #pragma unroll
    for (int r = 0; r < 4; ++r)
      gT[mw + (lane >> 4) * 4 + r][nw + (lane & 15)] = acc[r];
    __syncthreads();

    float pre[4];
    #pragma unroll
    for (int g = 0; g < 4; ++g) pre[g] = xv[g] + gT[b][g * SLICE + j];

    const float gi = sigf(pre[0]);
    const float gf = sigf(pre[1]);
    const float gg = tanh_fast(pre[2]);
    const float go = sigf(pre[3]);
    c = gf * c + gi * gg;
    const float h = go * tanh_fast(c);

    // publish h: pack 2x bf16 -> agent bypass dword store (lands in L3)
    {
      const u32 me  = (u32)f2bf(h);
      const u32 oth = (u32)__shfl_xor((int)me, 1);
      if ((j & 1) == 0) {
        u32* dst = (u32*)(hb_own + (size_t)t * (BATCH * HID) + b * HID + w * SLICE + j);
        __hip_atomic_store(dst, me | (oth << 16), __ATOMIC_RELAXED,
                           __HIP_MEMORY_SCOPE_AGENT);
      }
    }
    __syncthreads();   // compiler drains vmcnt(0) for all waves before barrier:
                       // all bypass h stores are at the coherence point here
    if (tid == 0) {
      __hip_atomic_store(&f_own[w], (u32)(t + 1), __ATOMIC_RELAXED,
                         __HIP_MEMORY_SCOPE_AGENT);
    }
    // dout stores AFTER the flag publish: HBM write latency off the critical
    // path (they drain at the next step's barrier). Nontemporal: don't dirty
    // the L2s that now cache h.
    if (layer == 1) {
      __builtin_nontemporal_store(h, &dout[((size_t)b * S_LEN + t) * HID + w * SLICE + j]);
      if (t == S_LEN - 1) {
        dout[(size_t)BATCH * S_LEN * HID + b * HID + w * SLICE + j] = h;
        dout[(size_t)BATCH * S_LEN * HID + (size_t)BATCH * HID + b * HID + w * SLICE + j] = c;
      }
    }
  }
}

// ---------------------------------------------------------------------------
extern "C" void kernel_launch(void* const* d_in, const int* in_sizes, int n_in,
                              void* d_out, int out_size, void* d_ws, size_t ws_size,
                              hipStream_t stream) {
  (void)in_sizes; (void)n_in; (void)out_size;
  const float* X   = (const float*)d_in[0];
  const float* Wih = (const float*)d_in[1];
  const float* Whh = (const float*)d_in[2];
  const float* bih = (const float*)d_in[3];
  const float* bhh = (const float*)d_in[4];

  const size_t M      = (size_t)S_LEN * BATCH;   // 65536
  const size_t xg_b32 = M * NG * 4;              // 512 MiB
  const size_t xg_b16 = M * NG * 2;
  const size_t hb_b   = M * HID * 2;             // 64 MiB
  const size_t w_b    = 2ull * NG * HID * 2;     // 4 MiB (both layers)
  const size_t fixed  = 2 * hb_b + 2 * w_b + 16384 + 1024;

  const int xg32 = (ws_size >= xg_b32 + fixed) ? 1 : 0;

  char* p = (char*)d_ws;
  auto carve = [&](size_t bytes) { char* q = p; p += (bytes + 255) & ~(size_t)255; return q; };
  void* xg     = carve(xg32 ? xg_b32 : xg_b16);
  u16*  hb1    = (u16*)carve(hb_b);
  u16*  hb2    = (u16*)carve(hb_b);
  u16*  wih_bf = (u16*)carve(w_b);
  u16*  whh_bf = (u16*)carve(w_b);
  float* bsum  = (float*)carve(16384);
  u32*  flags  = (u32*)carve(1024);

  hipMemsetAsync(flags, 0, 1024, stream);
  prep_weights<<<(2 * NG * HID) / 256, 256, 0, stream>>>(Wih, Whh, bih, bhh,
                                                         wih_bf, whh_bf, bsum);
  gemm_xg<<<dim3(32, 1024), 256, 0, stream>>>(X, wih_bf, bsum, xg, xg32);
  lstm_fused<<<2 * NWG, 256, 0, stream>>>(xg, xg32, whh_bf, wih_bf, bsum,
                                          hb1, hb2, (float*)d_out, flags);
}

// Round 3
// 8206.744 us; speedup vs baseline: 1.7777x; 1.7777x over previous
//
#include <hip/hip_runtime.h>

typedef unsigned short u16;
typedef unsigned int u32;
typedef unsigned long long u64;
typedef __attribute__((ext_vector_type(4))) float f32x4;
typedef __attribute__((ext_vector_type(8))) short bf16x8;

#define S_LEN 2048
#define BATCH 32
#define HID 512
#define NG 2048           // 4*HID
#define NWG 64            // recurrence workgroups per layer
#define SLICE 8           // hidden units per WG (HID/NWG)

#define MFMA16(a, b, c) __builtin_amdgcn_mfma_f32_16x16x32_bf16((a), (b), (c), 0, 0, 0)

__device__ __forceinline__ u16 f2bf(float f) {
  u32 u = __builtin_bit_cast(u32, f);
  u32 r = (u + 0x7FFFu + ((u >> 16) & 1u)) >> 16;   // RNE
  return (u16)r;
}
__device__ __forceinline__ float bf2f(u16 u) {
  u32 x = ((u32)u) << 16;
  return __builtin_bit_cast(float, x);
}
__device__ __forceinline__ float sigf(float x) {
  return 1.0f / (1.0f + __expf(-x));
}
__device__ __forceinline__ float tanh_fast(float x) {
  float a = fabsf(x);
  float t = __expf(-2.0f * a);
  float r = (1.0f - t) / (1.0f + t);
  return x < 0.0f ? -r : r;
}

// 16B cache-bypass load (sc0 sc1): reads the cross-XCD coherence point
// directly, like an agent-scope atomic load but full dwordx4 width.
// NOTE: vmcnt for this load is NOT tracked by the compiler — caller must
// execute bypass_wait() before consuming the result.
__device__ __forceinline__ uint4 bypass_ld16(const u16* p) {
  uint4 r;
  asm volatile("global_load_dwordx4 %0, %1, off sc0 sc1"
               : "=v"(r) : "v"(p) : "memory");
  return r;
}
__device__ __forceinline__ void bypass_wait() {
  asm volatile("s_waitcnt vmcnt(0)" ::: "memory");
  __builtin_amdgcn_sched_barrier(0);
}

// ---------------------------------------------------------------------------
// Weight prep: fp32 -> bf16 copies of W_ih / W_hh, bias sum.
// ---------------------------------------------------------------------------
__global__ void prep_weights(const float* __restrict__ Wih, const float* __restrict__ Whh,
                             const float* __restrict__ bih, const float* __restrict__ bhh,
                             u16* __restrict__ wih_bf, u16* __restrict__ whh_bf,
                             float* __restrict__ bsum) {
  const int i = blockIdx.x * 256 + threadIdx.x;   // grid covers exactly 2*NG*HID
  wih_bf[i] = f2bf(Wih[i]);
  whh_bf[i] = f2bf(Whh[i]);
  if (i < 2 * NG) bsum[i] = bih[i] + bhh[i];
}

// ---------------------------------------------------------------------------
// GEMM (layer-1 input contribution only):
//   xg[r][n] = sum_k X[b][t][k] * Wih1[n][k] + bias[n],  r = t*32+b
// 64x64 tiles, BK=64, 256 threads (4 waves, 2x2 quadrants of 32x32 each).
// ---------------------------------------------------------------------------
__global__ __launch_bounds__(256)
void gemm_xg(const float* __restrict__ Ap, const u16* __restrict__ Bw,
             const float* __restrict__ bias, void* __restrict__ xgp, int xg32)
{
  __shared__ __align__(16) u16 aT[64][72];
  __shared__ __align__(16) u16 bT[64][72];
  const int tid = threadIdx.x;
  const int nb = blockIdx.x;     // 0..31 (N tiles)
  const int mb = blockIdx.y;     // 0..1023 (M tiles)
  const int lane = tid & 63, wid = tid >> 6;
  const int mw = (wid & 1) * 32, nw = (wid >> 1) * 32;
  f32x4 acc[2][2] = {{{0.f,0.f,0.f,0.f},{0.f,0.f,0.f,0.f}},
                     {{0.f,0.f,0.f,0.f},{0.f,0.f,0.f,0.f}}};

  const int arow = tid >> 2;
  const int gm = mb * 64 + arow;
  const int t = gm >> 5, b = gm & 31;
  const size_t aoff = ((size_t)b * S_LEN + t) * HID;
  const size_t boff = (size_t)(nb * 64 + arow) * HID;
  const int c16 = (tid & 3) * 16;

  for (int kb = 0; kb < 8; ++kb) {
    const int k0 = kb * 64;
    {
      const float* src = Ap + aoff + k0 + c16;
      #pragma unroll
      for (int q = 0; q < 4; ++q) {
        const float4 v = ((const float4*)src)[q];
        ushort4 w4;
        w4.x = f2bf(v.x); w4.y = f2bf(v.y); w4.z = f2bf(v.z); w4.w = f2bf(v.w);
        *(ushort4*)&aT[arow][c16 + q * 4] = w4;
      }
    }
    {
      const uint4* src = (const uint4*)(Bw + boff + k0 + c16);
      const uint4 v0 = src[0], v1 = src[1];
      *(uint4*)&bT[arow][c16] = v0;
      *(uint4*)&bT[arow][c16 + 8] = v1;
    }
    __syncthreads();
    #pragma unroll
    for (int kk = 0; kk < 2; ++kk) {
      const int ko = kk * 32 + (lane >> 4) * 8;
      const bf16x8 a0 = *(const bf16x8*)&aT[mw +      (lane & 15)][ko];
      const bf16x8 a1 = *(const bf16x8*)&aT[mw + 16 + (lane & 15)][ko];
      const bf16x8 b0 = *(const bf16x8*)&bT[nw +      (lane & 15)][ko];
      const bf16x8 b1 = *(const bf16x8*)&bT[nw + 16 + (lane & 15)][ko];
      acc[0][0] = MFMA16(a0, b0, acc[0][0]);
      acc[0][1] = MFMA16(a0, b1, acc[0][1]);
      acc[1][0] = MFMA16(a1, b0, acc[1][0]);
      acc[1][1] = MFMA16(a1, b1, acc[1][1]);
    }
    __syncthreads();
  }
  const int col = lane & 15, rb = (lane >> 4) * 4;
  #pragma unroll
  for (int fm = 0; fm < 2; ++fm) {
    #pragma unroll
    for (int fn = 0; fn < 2; ++fn) {
      const int gn = nb * 64 + nw + fn * 16 + col;
      const float bv = bias[gn];
      #pragma unroll
      for (int r = 0; r < 4; ++r) {
        const size_t gmr = (size_t)(mb * 64 + mw + fm * 16 + rb + r);
        const float v = acc[fm][fn][r] + bv;
        if (xg32) ((float*)xgp)[gmr * NG + gn] = v;
        else      ((u16*)xgp)[gmr * NG + gn] = f2bf(v);
      }
    }
  }
}

// ---------------------------------------------------------------------------
// Fused 2-layer LSTM recurrence. 128 persistent WGs:
//   blocks 0..63   -> layer 1 (reads precomputed xg1)
//   blocks 64..127 -> layer 2, lagging one step, computing Wih2 @ h1[t] on the
//                     fly from LDS-resident Wih2 slice (no layer-2 GEMM).
//
// Handoff protocol (fence-free, all-bypass):
//   producer: bypass (agent-relaxed) h stores -> barrier (vmcnt(0) drain)
//             -> relaxed flag store. h is at the L3 coherence point before
//             the flag is visible.
//   consumer: poll flags with bypass loads; read h with 16B BYPASS loads
//             (sc0 sc1 dwordx4). Round-2 lesson: cached consumer reads of
//             bypass-published lines are ~2x slower than direct bypass
//             reads — the data path must stay bypass end-to-end.
// ---------------------------------------------------------------------------
__global__ __launch_bounds__(256, 1)
void lstm_fused(const void* __restrict__ xgp, int xg32,
                const u16* __restrict__ whh_bf, const u16* __restrict__ wih_bf,
                const float* __restrict__ bsum,
                u16* __restrict__ hb1, u16* __restrict__ hb2,
                float* __restrict__ dout, u32* __restrict__ flags)
{
  __shared__ __align__(16) u16 wR[32][520];   // recurrent weight slice (this layer)
  __shared__ __align__(16) u16 wI[32][520];   // layer 2 only: Wih2 slice
  __shared__ __align__(16) u16 hA[32][520];   // h1[t] (L2) or h1[t-1] (L1)
  __shared__ __align__(16) u16 hB[32][520];   // layer 2 only: h2[t-1]
  __shared__ float gT[32][33];                // gate tile (batch x 32 gate cols)

  const int blk = blockIdx.x;
  const int layer = blk >> 6;
  const int w = blk & 63;
  const int tid = threadIdx.x;
  const int lane = tid & 63, wid = tid >> 6;
  const int mw = (wid & 1) * 16, nw = (wid >> 1) * 16;
  const int b = tid >> 3, j = tid & 7;
  u32* f_l1  = flags;            // layer-1 flags [64]
  u32* f_own = flags + layer * 64;

  // stage recurrent weight slice: local row r = g*8+jj -> gate row g*512+w*8+jj
  const u16* Whh = whh_bf + (size_t)layer * NG * HID;
  #pragma unroll
  for (int i = tid; i < 32 * 64; i += 256) {
    const int r = i >> 6, ch = i & 63;
    const int gnrow = (r >> 3) * HID + w * SLICE + (r & 7);
    *(uint4*)&wR[r][ch * 8] = *(const uint4*)&Whh[(size_t)gnrow * HID + ch * 8];
  }
  float bv[4] = {0.f, 0.f, 0.f, 0.f};
  if (layer == 1) {
    const u16* Wih2 = wih_bf + (size_t)NG * HID;
    #pragma unroll
    for (int i = tid; i < 32 * 64; i += 256) {
      const int r = i >> 6, ch = i & 63;
      const int gnrow = (r >> 3) * HID + w * SLICE + (r & 7);
      *(uint4*)&wI[r][ch * 8] = *(const uint4*)&Wih2[(size_t)gnrow * HID + ch * 8];
    }
    #pragma unroll
    for (int g = 0; g < 4; ++g) bv[g] = bsum[NG + g * HID + w * SLICE + j];
  }
  u16* hb_own = layer ? hb2 : hb1;
  float c = 0.0f;
  __syncthreads();

  for (int t = 0; t < S_LEN; ++t) {
    float xv[4];

    if (layer == 0) {
      // prefetch xg1 for this step; loads in flight across the flag wait.
      // non-temporal: xg is streamed once, keep it out of L2/L3 (h lives there)
      if (xg32) {
        const float* x = (const float*)xgp + ((size_t)t * BATCH + b) * NG + w * SLICE + j;
        #pragma unroll
        for (int g = 0; g < 4; ++g) xv[g] = __builtin_nontemporal_load(&x[g * HID]);
      } else {
        const u16* x = (const u16*)xgp + ((size_t)t * BATCH + b) * NG + w * SLICE + j;
        #pragma unroll
        for (int g = 0; g < 4; ++g) xv[g] = bf2f(__builtin_nontemporal_load(&x[g * HID]));
      }
    } else {
      #pragma unroll
      for (int g = 0; g < 4; ++g) xv[g] = bv[g];
    }

    // ---- flag waits (no fences; data path is bypass-coherent) ----
    if (layer == 1) {
      if (wid == 0) {
        const u32 tgt = (u32)(t + 1);                 // h1[t] ready
        while (true) {
          u32 v = __hip_atomic_load(&f_l1[lane], __ATOMIC_RELAXED,
                                    __HIP_MEMORY_SCOPE_AGENT);
          if (__all((int)(v >= tgt))) break;
          __builtin_amdgcn_s_sleep(1);
        }
      } else if (wid == 1 && t > 0) {
        const u32 tgt = (u32)t;                       // own h2[t-1] ready
        while (true) {
          u32 v = __hip_atomic_load(&f_own[lane], __ATOMIC_RELAXED,
                                    __HIP_MEMORY_SCOPE_AGENT);
          if (__all((int)(v >= tgt))) break;
          __builtin_amdgcn_s_sleep(1);
        }
      }
    } else if (t > 0) {
      if (wid == 0) {
        const u32 tgt = (u32)t;                       // own h1[t-1] ready
        while (true) {
          u32 v = __hip_atomic_load(&f_own[lane], __ATOMIC_RELAXED,
                                    __HIP_MEMORY_SCOPE_AGENT);
          if (__all((int)(v >= tgt))) break;
          __builtin_amdgcn_s_sleep(1);
        }
      }
    }
    __syncthreads();

    // ---- stage h tiles (32x512 bf16 each) via 16B bypass loads ----
    const u16* srcA = nullptr;
    const u16* srcB = nullptr;
    if (layer == 1) {
      srcA = hb1 + (size_t)t * (BATCH * HID);
      if (t > 0) srcB = hb2 + (size_t)(t - 1) * (BATCH * HID);
    } else if (t > 0) {
      srcA = hb1 + (size_t)(t - 1) * (BATCH * HID);
    }
    uint4 vA[8], vB[8];
    if (srcA) {
      #pragma unroll
      for (int ii = 0; ii < 8; ++ii) {
        const int i = tid + ii * 256, r = i >> 6, cc = i & 63;
        vA[ii] = bypass_ld16(srcA + (size_t)r * HID + cc * 8);
      }
    }
    if (srcB) {
      #pragma unroll
      for (int ii = 0; ii < 8; ++ii) {
        const int i = tid + ii * 256, r = i >> 6, cc = i & 63;
        vB[ii] = bypass_ld16(srcB + (size_t)r * HID + cc * 8);
      }
    }
    bypass_wait();   // drain untracked asm loads before consuming
    if (srcA) {
      #pragma unroll
      for (int ii = 0; ii < 8; ++ii) {
        const int i = tid + ii * 256, r = i >> 6, cc = i & 63;
        *(uint4*)&hA[r][cc * 8] = vA[ii];
      }
    }
    if (srcB) {
      #pragma unroll
      for (int ii = 0; ii < 8; ++ii) {
        const int i = tid + ii * 256, r = i >> 6, cc = i & 63;
        *(uint4*)&hB[r][cc * 8] = vB[ii];
      }
    }
    __syncthreads();

    // ---- MFMA: two independent accumulator chains halve dep latency ----
    f32x4 ac0 = {0.f,0.f,0.f,0.f}, ac1 = {0.f,0.f,0.f,0.f};
    if (layer == 1) {
      #pragma unroll
      for (int kt = 0; kt < 16; ++kt) {
        const int ko = kt * 32 + (lane >> 4) * 8;
        const bf16x8 a  = *(const bf16x8*)&hA[mw + (lane & 15)][ko];
        const bf16x8 bb = *(const bf16x8*)&wI[nw + (lane & 15)][ko];
        if (kt & 1) ac1 = MFMA16(a, bb, ac1); else ac0 = MFMA16(a, bb, ac0);
      }
      if (t > 0) {
        #pragma unroll
        for (int kt = 0; kt < 16; ++kt) {
          const int ko = kt * 32 + (lane >> 4) * 8;
          const bf16x8 a  = *(const bf16x8*)&hB[mw + (lane & 15)][ko];
          const bf16x8 bb = *(const bf16x8*)&wR[nw + (lane & 15)][ko];
          if (kt & 1) ac1 = MFMA16(a, bb, ac1); else ac0 = MFMA16(a, bb, ac0);
        }
      }
    } else if (t > 0) {
      #pragma unroll
      for (int kt = 0; kt < 16; ++kt) {
        const int ko = kt * 32 + (lane >> 4) * 8;
        const bf16x8 a  = *(const bf16x8*)&hA[mw + (lane & 15)][ko];
        const bf16x8 bb = *(const bf16x8*)&wR[nw + (lane & 15)][ko];
        if (kt & 1) ac1 = MFMA16(a, bb, ac1); else ac0 = MFMA16(a, bb, ac0);
      }
    }
    const f32x4 acc = ac0 + ac1;

    // gate tile -> LDS -> per-(b,j) elementwise
    #pragma unroll
    for (int r = 0; r < 4; ++r)
      gT[mw + (lane >> 4) * 4 + r][nw + (lane & 15)] = acc[r];
    __syncthreads();

    float pre[4];
    #pragma unroll
    for (int g = 0; g < 4; ++g) pre[g] = xv[g] + gT[b][g * SLICE + j];

    const float gi = sigf(pre[0]);
    const float gf = sigf(pre[1]);
    const float gg = tanh_fast(pre[2]);
    const float go = sigf(pre[3]);
    c = gf * c + gi * gg;
    const float h = go * tanh_fast(c);

    // publish h: pack 2x bf16 -> agent bypass dword store (lands in L3)
    {
      const u32 me  = (u32)f2bf(h);
      const u32 oth = (u32)__shfl_xor((int)me, 1);
      if ((j & 1) == 0) {
        u32* dst = (u32*)(hb_own + (size_t)t * (BATCH * HID) + b * HID + w * SLICE + j);
        __hip_atomic_store(dst, me | (oth << 16), __ATOMIC_RELAXED,
                           __HIP_MEMORY_SCOPE_AGENT);
      }
    }
    __syncthreads();   // compiler drains vmcnt(0) for all waves before barrier:
                       // all bypass h stores are at the coherence point here
    if (tid == 0) {
      __hip_atomic_store(&f_own[w], (u32)(t + 1), __ATOMIC_RELAXED,
                         __HIP_MEMORY_SCOPE_AGENT);
    }
    // dout stores AFTER the flag publish: the HBM write completes during the
    // next step's poll phase, off the critical path. Plain cached stores
    // (L2-absorbed, lazily evicted; dout lines are never re-read).
    if (layer == 1) {
      dout[((size_t)b * S_LEN + t) * HID + w * SLICE + j] = h;
      if (t == S_LEN - 1) {
        dout[(size_t)BATCH * S_LEN * HID + b * HID + w * SLICE + j] = h;
        dout[(size_t)BATCH * S_LEN * HID + (size_t)BATCH * HID + b * HID + w * SLICE + j] = c;
      }
    }
  }
}

// ---------------------------------------------------------------------------
extern "C" void kernel_launch(void* const* d_in, const int* in_sizes, int n_in,
                              void* d_out, int out_size, void* d_ws, size_t ws_size,
                              hipStream_t stream) {
  (void)in_sizes; (void)n_in; (void)out_size;
  const float* X   = (const float*)d_in[0];
  const float* Wih = (const float*)d_in[1];
  const float* Whh = (const float*)d_in[2];
  const float* bih = (const float*)d_in[3];
  const float* bhh = (const float*)d_in[4];

  const size_t M      = (size_t)S_LEN * BATCH;   // 65536
  const size_t xg_b32 = M * NG * 4;              // 512 MiB
  const size_t xg_b16 = M * NG * 2;
  const size_t hb_b   = M * HID * 2;             // 64 MiB
  const size_t w_b    = 2ull * NG * HID * 2;     // 4 MiB (both layers)
  const size_t fixed  = 2 * hb_b + 2 * w_b + 16384 + 1024;

  const int xg32 = (ws_size >= xg_b32 + fixed) ? 1 : 0;

  char* p = (char*)d_ws;
  auto carve = [&](size_t bytes) { char* q = p; p += (bytes + 255) & ~(size_t)255; return q; };
  void* xg     = carve(xg32 ? xg_b32 : xg_b16);
  u16*  hb1    = (u16*)carve(hb_b);
  u16*  hb2    = (u16*)carve(hb_b);
  u16*  wih_bf = (u16*)carve(w_b);
  u16*  whh_bf = (u16*)carve(w_b);
  float* bsum  = (float*)carve(16384);
  u32*  flags  = (u32*)carve(1024);

  hipMemsetAsync(flags, 0, 1024, stream);
  prep_weights<<<(2 * NG * HID) / 256, 256, 0, stream>>>(Wih, Whh, bih, bhh,
                                                         wih_bf, whh_bf, bsum);
  gemm_xg<<<dim3(32, 1024), 256, 0, stream>>>(X, wih_bf, bsum, xg, xg32);
  lstm_fused<<<2 * NWG, 256, 0, stream>>>(xg, xg32, whh_bf, wih_bf, bsum,
                                          hb1, hb2, (float*)d_out, flags);
}

// Round 5
// 7891.873 us; speedup vs baseline: 1.8487x; 1.0399x over previous
//
#include <hip/hip_runtime.h>

typedef unsigned short u16;
typedef unsigned int u32;
typedef unsigned long long u64;
typedef __attribute__((ext_vector_type(4))) float f32x4;
typedef __attribute__((ext_vector_type(8))) short bf16x8;
typedef __attribute__((ext_vector_type(4))) u32 u32x4;   // asm-friendly 128-bit

#define S_LEN 2048
#define BATCH 32
#define HID 512
#define NG 2048           // 4*HID
#define NWG 64            // recurrence workgroups per layer
#define SLICE 8           // hidden units per WG (HID/NWG)

// Sentinel dword: two bf16 2.0 halves. |h| = |sigmoid*tanh| < 1 strictly, so
// no published h dword can ever equal this pattern.
#define SENT 0x40004000u

#define MFMA16(a, b, c) __builtin_amdgcn_mfma_f32_16x16x32_bf16((a), (b), (c), 0, 0, 0)

__device__ __forceinline__ u16 f2bf(float f) {
  u32 u = __builtin_bit_cast(u32, f);
  u32 r = (u + 0x7FFFu + ((u >> 16) & 1u)) >> 16;   // RNE
  return (u16)r;
}
__device__ __forceinline__ float bf2f(u16 u) {
  u32 x = ((u32)u) << 16;
  return __builtin_bit_cast(float, x);
}
__device__ __forceinline__ float sigf(float x) {
  return 1.0f / (1.0f + __expf(-x));
}
__device__ __forceinline__ float tanh_fast(float x) {
  float a = fabsf(x);
  float t = __expf(-2.0f * a);
  float r = (1.0f - t) / (1.0f + t);
  return x < 0.0f ? -r : r;
}

// 16B cache-bypass load/store (sc0 sc1): read/write the cross-XCD coherence
// point directly. vmcnt for these is NOT compiler-tracked — use bypass_wait()
// before consuming results. Operands are ext_vector_type (clang can't pass
// struct-typed uint4 as asm INPUT; ext vectors lower to VGPR quads).
__device__ __forceinline__ u32x4 bypass_ld16(const u16* p) {
  u32x4 r;
  asm volatile("global_load_dwordx4 %0, %1, off sc0 sc1"
               : "=v"(r) : "v"(p) : "memory");
  return r;
}
__device__ __forceinline__ void bypass_st16(u16* p, u32x4 v) {
  asm volatile("global_store_dwordx4 %0, %1, off sc0 sc1"
               :: "v"(p), "v"(v) : "memory");
}
__device__ __forceinline__ void bypass_wait() {
  asm volatile("s_waitcnt vmcnt(0)" ::: "memory");
  __builtin_amdgcn_sched_barrier(0);
}

// ---------------------------------------------------------------------------
// Sentinel fill for hb1+hb2 (contiguous 128 MiB). Bypass stores only: a
// cached fill would leave dirty sentinel lines in L2s that could evict later
// and clobber published h values at the coherence point.
// ---------------------------------------------------------------------------
__global__ void fill_sentinel(u16* base, int n16) {
  u32x4 v = {SENT, SENT, SENT, SENT};
  const int step = gridDim.x * 256;
  for (int i = blockIdx.x * 256 + threadIdx.x; i < n16; i += step)
    bypass_st16(base + (size_t)i * 8, v);
  asm volatile("s_waitcnt vmcnt(0)" ::: "memory");
}

// ---------------------------------------------------------------------------
// Weight prep: fp32 -> bf16 copies of W_ih / W_hh, bias sum.
// ---------------------------------------------------------------------------
__global__ void prep_weights(const float* __restrict__ Wih, const float* __restrict__ Whh,
                             const float* __restrict__ bih, const float* __restrict__ bhh,
                             u16* __restrict__ wih_bf, u16* __restrict__ whh_bf,
                             float* __restrict__ bsum) {
  const int i = blockIdx.x * 256 + threadIdx.x;   // grid covers exactly 2*NG*HID
  wih_bf[i] = f2bf(Wih[i]);
  whh_bf[i] = f2bf(Whh[i]);
  if (i < 2 * NG) bsum[i] = bih[i] + bhh[i];
}

// ---------------------------------------------------------------------------
// GEMM (layer-1 input contribution only):
//   xg[r][n] = sum_k X[b][t][k] * Wih1[n][k] + bias[n],  r = t*32+b
// 64x64 tiles, BK=64, 256 threads (4 waves, 2x2 quadrants of 32x32 each).
// ---------------------------------------------------------------------------
__global__ __launch_bounds__(256)
void gemm_xg(const float* __restrict__ Ap, const u16* __restrict__ Bw,
             const float* __restrict__ bias, void* __restrict__ xgp, int xg32)
{
  __shared__ __align__(16) u16 aT[64][72];
  __shared__ __align__(16) u16 bT[64][72];
  const int tid = threadIdx.x;
  const int nb = blockIdx.x;     // 0..31 (N tiles)
  const int mb = blockIdx.y;     // 0..1023 (M tiles)
  const int lane = tid & 63, wid = tid >> 6;
  const int mw = (wid & 1) * 32, nw = (wid >> 1) * 32;
  f32x4 acc[2][2] = {{{0.f,0.f,0.f,0.f},{0.f,0.f,0.f,0.f}},
                     {{0.f,0.f,0.f,0.f},{0.f,0.f,0.f,0.f}}};

  const int arow = tid >> 2;
  const int gm = mb * 64 + arow;
  const int t = gm >> 5, b = gm & 31;
  const size_t aoff = ((size_t)b * S_LEN + t) * HID;
  const size_t boff = (size_t)(nb * 64 + arow) * HID;
  const int c16 = (tid & 3) * 16;

  for (int kb = 0; kb < 8; ++kb) {
    const int k0 = kb * 64;
    {
      const float* src = Ap + aoff + k0 + c16;
      #pragma unroll
      for (int q = 0; q < 4; ++q) {
        const float4 v = ((const float4*)src)[q];
        ushort4 w4;
        w4.x = f2bf(v.x); w4.y = f2bf(v.y); w4.z = f2bf(v.z); w4.w = f2bf(v.w);
        *(ushort4*)&aT[arow][c16 + q * 4] = w4;
      }
    }
    {
      const uint4* src = (const uint4*)(Bw + boff + k0 + c16);
      const uint4 v0 = src[0], v1 = src[1];
      *(uint4*)&bT[arow][c16] = v0;
      *(uint4*)&bT[arow][c16 + 8] = v1;
    }
    __syncthreads();
    #pragma unroll
    for (int kk = 0; kk < 2; ++kk) {
      const int ko = kk * 32 + (lane >> 4) * 8;
      const bf16x8 a0 = *(const bf16x8*)&aT[mw +      (lane & 15)][ko];
      const bf16x8 a1 = *(const bf16x8*)&aT[mw + 16 + (lane & 15)][ko];
      const bf16x8 b0 = *(const bf16x8*)&bT[nw +      (lane & 15)][ko];
      const bf16x8 b1 = *(const bf16x8*)&bT[nw + 16 + (lane & 15)][ko];
      acc[0][0] = MFMA16(a0, b0, acc[0][0]);
      acc[0][1] = MFMA16(a0, b1, acc[0][1]);
      acc[1][0] = MFMA16(a1, b0, acc[1][0]);
      acc[1][1] = MFMA16(a1, b1, acc[1][1]);
    }
    __syncthreads();
  }
  const int col = lane & 15, rb = (lane >> 4) * 4;
  #pragma unroll
  for (int fm = 0; fm < 2; ++fm) {
    #pragma unroll
    for (int fn = 0; fn < 2; ++fn) {
      const int gn = nb * 64 + nw + fn * 16 + col;
      const float bv = bias[gn];
      #pragma unroll
      for (int r = 0; r < 4; ++r) {
        const size_t gmr = (size_t)(mb * 64 + mw + fm * 16 + rb + r);
        const float v = acc[fm][fn][r] + bv;
        if (xg32) ((float*)xgp)[gmr * NG + gn] = v;
        else      ((u16*)xgp)[gmr * NG + gn] = f2bf(v);
      }
    }
  }
}

// ---------------------------------------------------------------------------
// Fused 2-layer LSTM recurrence. 128 persistent WGs:
//   blocks 0..63   -> layer 1 (reads precomputed xg1)
//   blocks 64..127 -> layer 2, lagging one step, computing Wih2 @ h1[t] on the
//                     fly from LDS-resident Wih2 slice (no layer-2 GEMM).
//
// DATA-IS-THE-FLAG handoff: hb1/hb2 are pre-filled with SENT (bf16 2.0 pair,
// unreachable since |h|<1). Producers publish h with fire-and-forget bypass
// dword stores (no drain, no flag, no trailing barrier). Each consumer WAVE
// polls its own quarter of the needed h tile with 16B bypass loads until no
// dword equals SENT (per-dword store atomicity makes the check sound), then
// writes LDS; the barrier after the LDS write is the cross-wave combine.
// This collapses the previous publish-drain + flag-poll + data-load chain
// (~3 L3 round trips) to ~1.
// ---------------------------------------------------------------------------
__global__ __launch_bounds__(256, 1)
void lstm_fused(const void* __restrict__ xgp, int xg32,
                const u16* __restrict__ whh_bf, const u16* __restrict__ wih_bf,
                const float* __restrict__ bsum,
                u16* __restrict__ hb1, u16* __restrict__ hb2,
                float* __restrict__ dout)
{
  __shared__ __align__(16) u16 wR[32][520];   // recurrent weight slice (this layer)
  __shared__ __align__(16) u16 wI[32][520];   // layer 2 only: Wih2 slice
  __shared__ __align__(16) u16 hA[32][520];   // h1[t] (L2) or h1[t-1] (L1)
  __shared__ __align__(16) u16 hB[32][520];   // layer 2 only: h2[t-1]
  __shared__ float gT[32][33];                // gate tile (batch x 32 gate cols)

  const int blk = blockIdx.x;
  const int layer = blk >> 6;
  const int w = blk & 63;
  const int tid = threadIdx.x;
  const int lane = tid & 63, wid = tid >> 6;
  const int mw = (wid & 1) * 16, nw = (wid >> 1) * 16;
  const int b = tid >> 3, j = tid & 7;

  // stage recurrent weight slice: local row r = g*8+jj -> gate row g*512+w*8+jj
  const u16* Whh = whh_bf + (size_t)layer * NG * HID;
  #pragma unroll
  for (int i = tid; i < 32 * 64; i += 256) {
    const int r = i >> 6, ch = i & 63;
    const int gnrow = (r >> 3) * HID + w * SLICE + (r & 7);
    *(uint4*)&wR[r][ch * 8] = *(const uint4*)&Whh[(size_t)gnrow * HID + ch * 8];
  }
  float bv[4] = {0.f, 0.f, 0.f, 0.f};
  if (layer == 1) {
    const u16* Wih2 = wih_bf + (size_t)NG * HID;
    #pragma unroll
    for (int i = tid; i < 32 * 64; i += 256) {
      const int r = i >> 6, ch = i & 63;
      const int gnrow = (r >> 3) * HID + w * SLICE + (r & 7);
      *(uint4*)&wI[r][ch * 8] = *(const uint4*)&Wih2[(size_t)gnrow * HID + ch * 8];
    }
    #pragma unroll
    for (int g = 0; g < 4; ++g) bv[g] = bsum[NG + g * HID + w * SLICE + j];
  }
  u16* hb_own = layer ? hb2 : hb1;
  float c = 0.0f;
  __syncthreads();

  for (int t = 0; t < S_LEN; ++t) {
    float xv[4];

    if (layer == 0) {
      // prefetch xg1 for this step; loads in flight across the poll.
      // non-temporal: xg is streamed once, keep it out of L2/L3 (h lives there)
      if (xg32) {
        const float* x = (const float*)xgp + ((size_t)t * BATCH + b) * NG + w * SLICE + j;
        #pragma unroll
        for (int g = 0; g < 4; ++g) xv[g] = __builtin_nontemporal_load(&x[g * HID]);
      } else {
        const u16* x = (const u16*)xgp + ((size_t)t * BATCH + b) * NG + w * SLICE + j;
        #pragma unroll
        for (int g = 0; g < 4; ++g) xv[g] = bf2f(__builtin_nontemporal_load(&x[g * HID]));
      }
    } else {
      #pragma unroll
      for (int g = 0; g < 4; ++g) xv[g] = bv[g];
    }

    // ---- poll-load h tiles (data is the flag) ----
    const u16* srcA = nullptr;
    const u16* srcB = nullptr;
    if (layer == 1) {
      srcA = hb1 + (size_t)t * (BATCH * HID);
      if (t > 0) srcB = hb2 + (size_t)(t - 1) * (BATCH * HID);
    } else if (t > 0) {
      srcA = hb1 + (size_t)(t - 1) * (BATCH * HID);
    }
    u32x4 vA[8], vB[8];
    if (srcA) {
      while (true) {
        #pragma unroll
        for (int ii = 0; ii < 8; ++ii) {
          const int i = tid + ii * 256, r = i >> 6, cc = i & 63;
          vA[ii] = bypass_ld16(srcA + (size_t)r * HID + cc * 8);
        }
        if (srcB) {
          #pragma unroll
          for (int ii = 0; ii < 8; ++ii) {
            const int i = tid + ii * 256, r = i >> 6, cc = i & 63;
            vB[ii] = bypass_ld16(srcB + (size_t)r * HID + cc * 8);
          }
        }
        bypass_wait();   // drain untracked asm loads before checking
        u32 bad = 0;
        #pragma unroll
        for (int ii = 0; ii < 8; ++ii)
          bad |= (u32)(vA[ii][0] == SENT) | (u32)(vA[ii][1] == SENT) |
                 (u32)(vA[ii][2] == SENT) | (u32)(vA[ii][3] == SENT);
        if (srcB) {
          #pragma unroll
          for (int ii = 0; ii < 8; ++ii)
            bad |= (u32)(vB[ii][0] == SENT) | (u32)(vB[ii][1] == SENT) |
                   (u32)(vB[ii][2] == SENT) | (u32)(vB[ii][3] == SENT);
        }
        if (__all((int)(bad == 0))) break;   // wave's quarter fully published
      }
      #pragma unroll
      for (int ii = 0; ii < 8; ++ii) {
        const int i = tid + ii * 256, r = i >> 6, cc = i & 63;
        *(u32x4*)&hA[r][cc * 8] = vA[ii];
      }
      if (srcB) {
        #pragma unroll
        for (int ii = 0; ii < 8; ++ii) {
          const int i = tid + ii * 256, r = i >> 6, cc = i & 63;
          *(u32x4*)&hB[r][cc * 8] = vB[ii];
        }
      }
    }
    __syncthreads();   // barrier #1: all four waves' quarters valid + in LDS

    // ---- MFMA: two independent accumulator chains halve dep latency ----
    f32x4 ac0 = {0.f,0.f,0.f,0.f}, ac1 = {0.f,0.f,0.f,0.f};
    if (layer == 1) {
      #pragma unroll
      for (int kt = 0; kt < 16; ++kt) {
        const int ko = kt * 32 + (lane >> 4) * 8;
        const bf16x8 a  = *(const bf16x8*)&hA[mw + (lane & 15)][ko];
        const bf16x8 bb = *(const bf16x8*)&wI[nw + (lane & 15)][ko];
        if (kt & 1) ac1 = MFMA16(a, bb, ac1); else ac0 = MFMA16(a, bb, ac0);
      }
      if (t > 0) {
        #pragma unroll
        for (int kt = 0; kt < 16; ++kt) {
          const int ko = kt * 32 + (lane >> 4) * 8;
          const bf16x8 a  = *(const bf16x8*)&hB[mw + (lane & 15)][ko];
          const bf16x8 bb = *(const bf16x8*)&wR[nw + (lane & 15)][ko];
          if (kt & 1) ac1 = MFMA16(a, bb, ac1); else ac0 = MFMA16(a, bb, ac0);
        }
      }
    } else if (t > 0) {
      #pragma unroll
      for (int kt = 0; kt < 16; ++kt) {
        const int ko = kt * 32 + (lane >> 4) * 8;
        const bf16x8 a  = *(const bf16x8*)&hA[mw + (lane & 15)][ko];
        const bf16x8 bb = *(const bf16x8*)&wR[nw + (lane & 15)][ko];
        if (kt & 1) ac1 = MFMA16(a, bb, ac1); else ac0 = MFMA16(a, bb, ac0);
      }
    }
    const f32x4 acc = ac0 + ac1;

    // gate tile -> LDS -> per-(b,j) elementwise
    #pragma unroll
    for (int r = 0; r < 4; ++r)
      gT[mw + (lane >> 4) * 4 + r][nw + (lane & 15)] = acc[r];
    __syncthreads();   // barrier #2: gT ready; all waves done reading hA/hB

    float pre[4];
    #pragma unroll
    for (int g = 0; g < 4; ++g) pre[g] = xv[g] + gT[b][g * SLICE + j];

    const float gi = sigf(pre[0]);
    const float gf = sigf(pre[1]);
    const float gg = tanh_fast(pre[2]);
    const float go = sigf(pre[3]);
    c = gf * c + gi * gg;
    const float h = go * tanh_fast(c);

    // publish h: pack 2x bf16 -> fire-and-forget bypass dword store. The
    // store IS the signal (consumers poll for != SENT). No drain, no flag,
    // no trailing barrier.
    {
      const u32 me  = (u32)f2bf(h);
      const u32 oth = (u32)__shfl_xor((int)me, 1);
      if ((j & 1) == 0) {
        u32* dst = (u32*)(hb_own + (size_t)t * (BATCH * HID) + b * HID + w * SLICE + j);
        asm volatile("global_store_dword %0, %1, off sc0 sc1"
                     :: "v"(dst), "v"(me | (oth << 16)) : "memory");
      }
    }
    // dout stores: plain cached, off the critical path (drain lazily).
    if (layer == 1) {
      dout[((size_t)b * S_LEN + t) * HID + w * SLICE + j] = h;
      if (t == S_LEN - 1) {
        dout[(size_t)BATCH * S_LEN * HID + b * HID + w * SLICE + j] = h;
        dout[(size_t)BATCH * S_LEN * HID + (size_t)BATCH * HID + b * HID + w * SLICE + j] = c;
      }
    }
  }
}

// ---------------------------------------------------------------------------
extern "C" void kernel_launch(void* const* d_in, const int* in_sizes, int n_in,
                              void* d_out, int out_size, void* d_ws, size_t ws_size,
                              hipStream_t stream) {
  (void)in_sizes; (void)n_in; (void)out_size;
  const float* X   = (const float*)d_in[0];
  const float* Wih = (const float*)d_in[1];
  const float* Whh = (const float*)d_in[2];
  const float* bih = (const float*)d_in[3];
  const float* bhh = (const float*)d_in[4];

  const size_t M      = (size_t)S_LEN * BATCH;   // 65536
  const size_t xg_b32 = M * NG * 4;              // 512 MiB
  const size_t xg_b16 = M * NG * 2;
  const size_t hb_b   = M * HID * 2;             // 64 MiB
  const size_t w_b    = 2ull * NG * HID * 2;     // 4 MiB (both layers)
  const size_t fixed  = 2 * hb_b + 2 * w_b + 16384 + 1024;

  const int xg32 = (ws_size >= xg_b32 + fixed) ? 1 : 0;

  char* p = (char*)d_ws;
  auto carve = [&](size_t bytes) { char* q = p; p += (bytes + 255) & ~(size_t)255; return q; };
  void* xg     = carve(xg32 ? xg_b32 : xg_b16);
  u16*  hb1    = (u16*)carve(hb_b);
  u16*  hb2    = (u16*)carve(hb_b);   // contiguous with hb1
  u16*  wih_bf = (u16*)carve(w_b);
  u16*  whh_bf = (u16*)carve(w_b);
  float* bsum  = (float*)carve(16384);

  // sentinel-fill hb1+hb2 (contiguous 128 MiB) every launch: bench-iteration
  // reuse must never satisfy the data-poll with stale state.
  fill_sentinel<<<2048, 256, 0, stream>>>(hb1, (int)((2 * hb_b) / 16));
  prep_weights<<<(2 * NG * HID) / 256, 256, 0, stream>>>(Wih, Whh, bih, bhh,
                                                         wih_bf, whh_bf, bsum);
  gemm_xg<<<dim3(32, 1024), 256, 0, stream>>>(X, wih_bf, bsum, xg, xg32);
  lstm_fused<<<2 * NWG, 256, 0, stream>>>(xg, xg32, whh_bf, wih_bf, bsum,
                                          hb1, hb2, (float*)d_out);
}